// Round 4
// baseline (356.020 us; speedup 1.0000x reference)
//
#include <hip/hip_runtime.h>
#include <math.h>

#define TV 3200          // T*V = 128*25
#define NTV 204800       // N*T*V
#define NBLK 256         // grid: one block per (n, 32-t tile); 1/CU -> co-residency guaranteed
#define TT 32            // t-tile
#define SITES 800        // TT*25 sites per block
constexpr float EPSF = 1e-5f;

// fast tanh: 1 - 2/(e^{2x}+1); exact saturation, ~1e-7 abs err in operating range
__device__ inline float fast_tanh(float x){
  float e = __expf(2.f*x);
  return 1.f - 2.f/(e + 1.f);
}

// device-scope grid barrier; co-residency guaranteed by NBLK=256 <= #CU
__device__ inline void grid_barrier(int* bar, int idx){
  __threadfence();                    // release prior global writes (agent scope)
  __syncthreads();
  if (threadIdx.x == 0){
    __hip_atomic_fetch_add(&bar[idx], 1, __ATOMIC_ACQ_REL, __HIP_MEMORY_SCOPE_AGENT);
    int iter = 0;
    while (__hip_atomic_load(&bar[idx], __ATOMIC_ACQUIRE, __HIP_MEMORY_SCOPE_AGENT) < NBLK){
      if (++iter > (1 << 24)) break;  // hang guard (~1s); real wait is microseconds
    }
  }
  __syncthreads();
}

__global__ void k_init(int* bar){ if (threadIdx.x < 16) bar[threadIdx.x] = 0; }

// partial-stat writer for 8-wave (512-thread) blocks
template<int NS>
__device__ inline void write_partials8(float (&vals)[NS], float* __restrict__ outp, float* lds){
  int lane = threadIdx.x & 63;
  int wid  = threadIdx.x >> 6;    // 0..7
  #pragma unroll
  for (int s = 0; s < NS; ++s){
    float v = vals[s];
    #pragma unroll
    for (int o = 32; o > 0; o >>= 1) v += __shfl_down(v, o);
    if (lane == 0) lds[s*8 + wid] = v;
  }
  __syncthreads();
  if ((int)threadIdx.x < NS){
    float t = 0.f;
    #pragma unroll
    for (int w = 0; w < 8; ++w) t += lds[threadIdx.x*8 + w];
    outp[threadIdx.x*NBLK + blockIdx.x] = t;
  }
}

__global__ __launch_bounds__(512) void k_fused(
    const float* __restrict__ x,
    const float* __restrict__ Wv, const float* __restrict__ bv,
    const float* __restrict__ Ww, const float* __restrict__ bw,
    const float* __restrict__ g_bn, const float* __restrict__ b_bn,
    const float* __restrict__ Wr, const float* __restrict__ br,
    const float* __restrict__ g_r, const float* __restrict__ b_r,
    const float* __restrict__ Wo, const float* __restrict__ bo,
    const float* __restrict__ g_o, const float* __restrict__ b_o,
    float* __restrict__ out,
    float* __restrict__ haloV, float* __restrict__ haloS,
    float* __restrict__ pr, float* __restrict__ patt, float* __restrict__ ph,
    int* __restrict__ bar)
{
  __shared__ float sV[36*25*9];     // v0 tile + 2-slice halos, r-dim padded to 9 (bank-conflict-free)
  __shared__ float sS[36*25];       // s tile + halos
  __shared__ float sWv[512], sWr[512];
  __shared__ float sWw[125], sbw[25];
  __shared__ float red[44*8];       // per-wave reduction scratch
  __shared__ float sc[32];          // BN coefs
  __shared__ float hstat[44];
  __shared__ float sW[1024], sB[128];   // folded Wo', bo'

  const int tid = threadIdx.x;
  const int b = blockIdx.x;
  const int n = b >> 2, q = b & 3;
  const int t0 = q*TT;
  const bool act1 = (tid < SITES - 512);    // 288 threads own a 2nd site

  if (tid < 512){ sWv[tid] = Wv[tid]; sWr[tid] = Wr[tid]; }
  if (tid < 125) sWw[tid] = Ww[tid];
  if (tid < 25)  sbw[tid] = bw[tid];
  __syncthreads();

  float r0v[2][8], attv[2][8], hv[2][8];
  #pragma unroll
  for (int sl = 0; sl < 2; ++sl)
    #pragma unroll
    for (int r = 0; r < 8; ++r){ r0v[sl][r] = 0.f; attv[sl][r] = 0.f; hv[sl][r] = 0.f; }

  // ==== Phase A: x -> v0 (LDS+halo), s (LDS+halo), r0 (regs) ====
  #pragma unroll
  for (int sl = 0; sl < 2; ++sl){
    bool act = (sl == 0) || act1;
    if (act){
      int L = tid + sl*512;
      int tl = L/25, v = L - tl*25;
      const float* xp = x + (size_t)n*64*TV + (size_t)(t0+tl)*25 + v;
      float ssum = 0.f;
      float av[8] = {0,0,0,0,0,0,0,0};
      float arr[8] = {0,0,0,0,0,0,0,0};
      #pragma unroll 8
      for (int c = 0; c < 64; ++c){
        float xv = xp[(size_t)c*TV];
        ssum += xv;
        #pragma unroll
        for (int r = 0; r < 8; ++r){
          av[r]  = fmaf(sWv[r*64+c], xv, av[r]);
          arr[r] = fmaf(sWr[r*64+c], xv, arr[r]);
        }
      }
      float sval = ssum * 0.015625f;
      sS[(tl+2)*25 + v] = sval;
      int lb = ((tl+2)*25 + v)*9;
      #pragma unroll
      for (int r = 0; r < 8; ++r){
        sV[lb + r]  = av[r] + bv[r];
        r0v[sl][r] = arr[r] + br[r];
      }
      if (tl < 2){                       // my first 2 slices serve left neighbor's right... (side 0)
        int base = ((b*2 + 0)*2 + tl)*25 + v;
        haloS[base] = sval;
        #pragma unroll
        for (int r = 0; r < 8; ++r) haloV[base*8 + r] = av[r] + bv[r];
      }
      if (tl >= TT-2){                   // my last 2 slices (side 1)
        int base = ((b*2 + 1)*2 + (tl-(TT-2)))*25 + v;
        haloS[base] = sval;
        #pragma unroll
        for (int r = 0; r < 8; ++r) haloV[base*8 + r] = av[r] + bv[r];
      }
    }
  }
  {
    float vals[16];
    #pragma unroll
    for (int r = 0; r < 8; ++r){
      vals[r]   = r0v[0][r] + r0v[1][r];
      vals[8+r] = r0v[0][r]*r0v[0][r] + r0v[1][r]*r0v[1][r];
    }
    write_partials8<16>(vals, pr, red);
  }
  grid_barrier(bar, 0);

  // stage halos from neighbor blocks into LDS slices {0,1} and {34,35}
  for (int i = tid; i < 900; i += 512){
    if (i < 800){
      int side = i / 400;
      int j = i - side*400;             // 0..399
      int t2 = j / 200; int rem = j - t2*200; int v = rem >> 3; int r = rem & 7;
      if (side == 0){
        float val = (q > 0) ? haloV[((((b-1)*2+1)*2 + t2)*25 + v)*8 + r] : 0.f;
        sV[(t2*25 + v)*9 + r] = val;
      } else {
        float val = (q < 3) ? haloV[((((b+1)*2+0)*2 + t2)*25 + v)*8 + r] : 0.f;
        sV[((34+t2)*25 + v)*9 + r] = val;
      }
    } else {
      int j = i - 800;                  // 0..99
      int side = j / 50; int k2 = j - side*50; int t2 = k2/25; int v = k2 - t2*25;
      if (side == 0){
        sS[t2*25 + v] = (q > 0) ? haloS[(((b-1)*2+1)*2 + t2)*25 + v] : 0.f;
      } else {
        sS[(34+t2)*25 + v] = (q < 3) ? haloS[(((b+1)*2+0)*2 + t2)*25 + v] : 0.f;
      }
    }
  }
  __syncthreads();

  // ==== Phase B: w2 weights + att (regs) ====
  #pragma unroll
  for (int sl = 0; sl < 2; ++sl){
    bool act = (sl == 0) || act1;
    if (act){
      int L = tid + sl*512;
      int tl = L/25, v = L - tl*25;
      float m[5];
      #pragma unroll
      for (int k = 0; k < 5; ++k) m[k] = sS[(tl+k)*25 + v];
      float w2[5] = {0.f,0.f,0.f,0.f,0.f};
      #pragma unroll
      for (int w = 0; w < 5; ++w){
        #pragma unroll
        for (int u = 0; u < 5; ++u){
          int o = w*5 + u;
          float wo = sbw[o];
          #pragma unroll
          for (int k = 0; k < 5; ++k) wo = fmaf(sWw[o*5+k], m[k], wo);
          w2[u] += fast_tanh(wo);
        }
      }
      #pragma unroll
      for (int u = 0; u < 5; ++u){
        float wu = w2[u];
        int base = ((tl+u)*25 + v)*9;
        #pragma unroll
        for (int r = 0; r < 8; ++r) attv[sl][r] = fmaf(wu, sV[base + r], attv[sl][r]);
      }
    }
  }
  {
    float vals[16];
    #pragma unroll
    for (int r = 0; r < 8; ++r){
      vals[r]   = attv[0][r] + attv[1][r];
      vals[8+r] = attv[0][r]*attv[0][r] + attv[1][r]*attv[1][r];
    }
    write_partials8<16>(vals, patt, red);
  }
  grid_barrier(bar, 1);

  // ==== per-block BN coef reduce (redundant across blocks, cheap) ====
  {
    int g = tid >> 4;                   // 32 groups of 16 lanes
    int l4 = tid & 15;
    const float* src = (g < 16) ? (pr + g*NBLK) : (patt + (g-16)*NBLK);
    float sm = 0.f;
    for (int i = l4; i < NBLK; i += 16) sm += src[i];
    #pragma unroll
    for (int o = 8; o > 0; o >>= 1) sm += __shfl_down(sm, o, 16);
    if (l4 == 0) red[g] = sm;
  }
  __syncthreads();
  if (tid < 8){
    int r = tid;
    float mu_r  = red[r]     / (float)NTV;
    float var_r = red[8+r]   / (float)NTV - mu_r*mu_r;
    float ar_ = g_r[r] * rsqrtf(var_r + EPSF);
    sc[16+r] = ar_; sc[24+r] = b_r[r] - ar_*mu_r;
    float mu_a  = red[16+r]  / (float)NTV;
    float var_a = red[24+r]  / (float)NTV - mu_a*mu_a;
    float aa = g_bn[r] * rsqrtf(var_a + EPSF);
    sc[r] = aa; sc[8+r] = b_bn[r] - aa*mu_a;
  }
  __syncthreads();

  // ==== Phase C: h = leaky(bn(att)+bn(r0)) in regs; 44 partial moments ====
  #pragma unroll
  for (int sl = 0; sl < 2; ++sl){
    bool act = (sl == 0) || act1;
    if (act){
      #pragma unroll
      for (int r = 0; r < 8; ++r){
        float z = sc[r]*attv[sl][r] + sc[8+r] + sc[16+r]*r0v[sl][r] + sc[24+r];
        hv[sl][r] = (z >= 0.f) ? z : 0.1f*z;
      }
    }
  }
  {
    float vals[44];
    #pragma unroll
    for (int r = 0; r < 8; ++r) vals[r] = hv[0][r] + hv[1][r];
    int cnt = 8;
    #pragma unroll
    for (int r = 0; r < 8; ++r){
      #pragma unroll
      for (int r2 = r; r2 < 8; ++r2){
        vals[cnt++] = hv[0][r]*hv[0][r2] + hv[1][r]*hv[1][r2];
      }
    }
    write_partials8<44>(vals, ph, red);
  }
  grid_barrier(bar, 2);

  // ==== per-block h-stat reduce + BN fold (redundant across blocks) ====
  {
    int wid = tid >> 6, lane = tid & 63;
    for (int s = wid; s < 44; s += 8){
      float sm = 0.f;
      for (int i = lane; i < NBLK; i += 64) sm += ph[s*NBLK + i];
      #pragma unroll
      for (int o = 32; o > 0; o >>= 1) sm += __shfl_down(sm, o);
      if (lane == 0) hstat[s] = sm;
    }
  }
  __syncthreads();
  if (tid < 128){
    int o = tid;
    double muh[8];
    #pragma unroll
    for (int r = 0; r < 8; ++r) muh[r] = (double)hstat[r] / (double)NTV;
    double w[8];
    #pragma unroll
    for (int r = 0; r < 8; ++r) w[r] = (double)Wo[o*8+r];
    double bob = (double)bo[o];
    double mu = bob;
    #pragma unroll
    for (int r = 0; r < 8; ++r) mu += w[r]*muh[r];
    double t = 0.0;
    for (int r = 0; r < 8; ++r){
      for (int r2 = 0; r2 < 8; ++r2){
        int lo = (r < r2) ? r : r2, hi = (r < r2) ? r2 : r;
        int idx = 8 + lo*8 - (lo*(lo-1))/2 + (hi - lo);
        t += w[r]*w[r2]*((double)hstat[idx] / (double)NTV);
      }
    }
    double ey2 = t + 2.0*bob*(mu - bob) + bob*bob;
    double var = ey2 - mu*mu;
    double a = (double)g_o[o] / sqrt(var + (double)EPSF);
    #pragma unroll
    for (int r = 0; r < 8; ++r) sW[o*8+r] = (float)(a * w[r]);
    sB[o] = (float)(a * (bob - mu) + (double)b_o[o]);
  }
  __syncthreads();

  // ==== Phase E: out = fold . h + bfold ====
  #pragma unroll
  for (int sl = 0; sl < 2; ++sl){
    bool act = (sl == 0) || act1;
    if (act){
      int L = tid + sl*512;
      int tl = L/25, v = L - tl*25;
      float* op = out + (size_t)n*128*TV + (size_t)(t0+tl)*25 + v;
      #pragma unroll 8
      for (int o = 0; o < 128; ++o){
        float y = sB[o];
        #pragma unroll
        for (int r = 0; r < 8; ++r) y = fmaf(sW[o*8+r], hv[sl][r], y);
        __builtin_nontemporal_store(y, op + (size_t)o*TV);
      }
    }
  }
}

extern "C" void kernel_launch(void* const* d_in, const int* in_sizes, int n_in,
                              void* d_out, int out_size, void* d_ws, size_t ws_size,
                              hipStream_t stream){
  const float* x    = (const float*)d_in[0];
  const float* Wv   = (const float*)d_in[1];
  const float* bv   = (const float*)d_in[2];
  const float* Ww   = (const float*)d_in[3];
  const float* bw   = (const float*)d_in[4];
  const float* g_bn = (const float*)d_in[5];
  const float* b_bn = (const float*)d_in[6];
  const float* Wr   = (const float*)d_in[7];
  const float* br   = (const float*)d_in[8];
  const float* g_r  = (const float*)d_in[9];
  const float* b_r  = (const float*)d_in[10];
  const float* Wo   = (const float*)d_in[11];
  const float* bo   = (const float*)d_in[12];
  const float* g_o  = (const float*)d_in[13];
  const float* b_o  = (const float*)d_in[14];

  float* ws = (float*)d_ws;
  size_t off = 0;
  float* haloV = ws + off; off += 204800;   // 256 blocks x 2 sides x 2 t x 25 v x 8 r
  float* haloS = ws + off; off += 51200;
  float* pr    = ws + off; off += 16*NBLK;
  float* patt  = ws + off; off += 16*NBLK;
  float* ph    = ws + off; off += 44*NBLK;
  int*   bar   = (int*)(ws + off); off += 16;

  k_init <<<1, 64, 0, stream>>>(bar);
  k_fused<<<NBLK, 512, 0, stream>>>(x, Wv, bv, Ww, bw, g_bn, b_bn, Wr, br, g_r, b_r,
                                    Wo, bo, g_o, b_o, (float*)d_out,
                                    haloV, haloS, pr, patt, ph, bar);
}